// Round 12
// baseline (203.309 us; speedup 1.0000x reference)
//
#include <hip/hip_runtime.h>
#include <hip/hip_bf16.h>
#include <math.h>

#define N_NODES 10000
#define D_MODEL 128
#define E_EDGES 320000
#define P_EDGES 80000
#define LN_EPS 1e-5f
#define NBUCK 40960        // 4*N padded
#define CAP 32             // slots per bucket (Poisson(8): P(>32) ~ 1e-11)
#define M_ROWS 50000
#define M_PAD  50048       // 782*64
#define NPAD   192         // delta(128) + bc(32) + 32 zero pad

typedef __attribute__((ext_vector_type(8))) short bf16x8;
typedef __attribute__((ext_vector_type(4))) float f32x4;

__device__ __forceinline__ unsigned short f2bf(float f) {
    __hip_bfloat16 h = __float2bfloat16(f);
    return *reinterpret_cast<unsigned short*>(&h);
}
__device__ __forceinline__ float bf2f(unsigned int u) {
    return __uint_as_float(u << 16);
}

// ---------------------------------------------------------------------------
// prep_all: pack Wcat(192) + Wg + W_out (B-frag layout), x/rel -> bf16 (x also
// into s=0 token rows; pad rows 10000-10047 zeroed), zero counters, pack ed4.
// gid: [0,24576) Bp | [24576,40960) Wgp | [40960,57344) Wop |
// [57344,98304) cnt | [98304,123904) rel_bf | [123904,1403904) x_bf |
// [1403904,1410048) x_bf pad | [1410048,1730048) ed4
// ---------------------------------------------------------------------------
__global__ __launch_bounds__(256) void prep_all(
    const float* __restrict__ Wd, const float* __restrict__ Wb,
    const float* __restrict__ Wc, const float* __restrict__ Wg,
    const float* __restrict__ W_out,
    const float* __restrict__ x, const float* __restrict__ rel,
    const int* __restrict__ edge_index, const int* __restrict__ edge_type,
    unsigned short* __restrict__ Bp, unsigned short* __restrict__ Wgp,
    unsigned short* __restrict__ Wop,
    unsigned short* __restrict__ x_bf, unsigned short* __restrict__ rel_bf,
    int* __restrict__ cnt, int4* __restrict__ ed4,
    unsigned short* __restrict__ tokens)
{
    int gid = blockIdx.x * 256 + threadIdx.x;
    if (gid < 24576) {
        int k = gid / NPAD, n = gid - (gid / NPAD) * NPAD;
        float v = 0.f;
        if (n < 128)      v = Wd[k * 128 + n];
        else if (n < 144) v = Wb[k * 16 + (n - 128)];
        else if (n < 160) v = Wc[k * 16 + (n - 144)];
        Bp[((size_t)(k >> 3) * NPAD + n) * 8 + (k & 7)] = f2bf(v);
    } else if (gid < 40960) {
        int i = gid - 24576;
        int k = i >> 7, n = i & 127;
        Wgp[((size_t)(k >> 3) * 128 + n) * 8 + (k & 7)] = f2bf(Wg[k * 128 + n]);
    } else if (gid < 57344) {
        int i = gid - 40960;
        int k = i >> 7, n = i & 127;
        Wop[((size_t)(k >> 3) * 128 + n) * 8 + (k & 7)] = f2bf(W_out[k * 128 + n]);
    } else if (gid < 98304) {
        cnt[gid - 57344] = 0;
    } else if (gid < 123904) {
        int i = gid - 98304;
        rel_bf[i] = f2bf(rel[i]);
    } else if (gid < 1403904) {
        int i = gid - 123904;
        unsigned short v = f2bf(x[i]);
        x_bf[i] = v;
        tokens[(size_t)(i >> 7) * 640 + (i & 127)] = v;   // s=0 token row
    } else if (gid < 1410048) {
        x_bf[1280000 + (gid - 1403904)] = 0;               // pad rows for g_gemm
    } else if (gid < 1730048) {
        int e = gid - 1410048;
        ed4[e] = make_int4(edge_index[e], edge_index[E_EDGES + e], edge_type[e], 0);
    }
}

// ---------------------------------------------------------------------------
// One-pass CSR into fixed-capacity bucket slots (1 random 16B load per edge).
// ---------------------------------------------------------------------------
__global__ __launch_bounds__(256) void csr_build(
    const int4* __restrict__ ed4, const int* __restrict__ perms,
    int* __restrict__ cnt, int2* __restrict__ slots)
{
    int gid = blockIdx.x * blockDim.x + threadIdx.x;
    if (gid >= 4 * P_EDGES) return;
    int s = gid / P_EDGES;
    int e = perms[gid];
    int4 ed = ed4[e];
    int b = ed.y * 4 + s;
    int pos = atomicAdd(&cnt[b], 1);
    if (pos < CAP) slots[(size_t)b * CAP + pos] = make_int2(ed.x, ed.z);
}

// ---------------------------------------------------------------------------
// Gather (wide: 10000 blocks): one wave per bucket; lane = 2 dims;
// 4 edges in flight.
// ---------------------------------------------------------------------------
__global__ __launch_bounds__(256) void gather_tokens(
    const unsigned short* __restrict__ x_bf,
    const int* __restrict__ cnt, const int2* __restrict__ slots,
    const unsigned short* __restrict__ rel_bf,
    unsigned short* __restrict__ tokens)
{
    int n = blockIdx.x;
    int w = threadIdx.x >> 6, lane = threadIdx.x & 63;
    int b = n * 4 + w;
    int c = cnt[b];
    int cc = c < CAP ? c : CAP;
    const int2* sl = slots + (size_t)b * CAP;
    const unsigned int* xu = (const unsigned int*)x_bf;
    const unsigned int* ru = (const unsigned int*)rel_bf;
    float ax = 0.f, ay = 0.f;
    int j = 0;
    for (; j + 4 <= cc; j += 4) {
        int4 e01 = *(const int4*)(sl + j);
        int4 e23 = *(const int4*)(sl + j + 2);
        unsigned int x0 = xu[(size_t)e01.x * 64 + lane];
        unsigned int r0 = ru[(size_t)e01.y * 64 + lane];
        unsigned int x1 = xu[(size_t)e01.z * 64 + lane];
        unsigned int r1 = ru[(size_t)e01.w * 64 + lane];
        unsigned int x2 = xu[(size_t)e23.x * 64 + lane];
        unsigned int r2 = ru[(size_t)e23.y * 64 + lane];
        unsigned int x3 = xu[(size_t)e23.z * 64 + lane];
        unsigned int r3 = ru[(size_t)e23.w * 64 + lane];
        ax += (bf2f(x0 & 0xffffu) + bf2f(r0 & 0xffffu))
            + (bf2f(x1 & 0xffffu) + bf2f(r1 & 0xffffu))
            + (bf2f(x2 & 0xffffu) + bf2f(r2 & 0xffffu))
            + (bf2f(x3 & 0xffffu) + bf2f(r3 & 0xffffu));
        ay += (bf2f(x0 >> 16) + bf2f(r0 >> 16))
            + (bf2f(x1 >> 16) + bf2f(r1 >> 16))
            + (bf2f(x2 >> 16) + bf2f(r2 >> 16))
            + (bf2f(x3 >> 16) + bf2f(r3 >> 16));
    }
    if (j + 2 <= cc) {
        int4 e01 = *(const int4*)(sl + j);
        unsigned int x0 = xu[(size_t)e01.x * 64 + lane];
        unsigned int r0 = ru[(size_t)e01.y * 64 + lane];
        unsigned int x1 = xu[(size_t)e01.z * 64 + lane];
        unsigned int r1 = ru[(size_t)e01.w * 64 + lane];
        ax += (bf2f(x0 & 0xffffu) + bf2f(r0 & 0xffffu))
            + (bf2f(x1 & 0xffffu) + bf2f(r1 & 0xffffu));
        ay += (bf2f(x0 >> 16) + bf2f(r0 >> 16))
            + (bf2f(x1 >> 16) + bf2f(r1 >> 16));
        j += 2;
    }
    if (j < cc) {
        int2 se = sl[j];
        unsigned int xa = xu[(size_t)se.x * 64 + lane];
        unsigned int ra = ru[(size_t)se.y * 64 + lane];
        ax += bf2f(xa & 0xffffu) + bf2f(ra & 0xffffu);
        ay += bf2f(xa >> 16) + bf2f(ra >> 16);
    }
    float inv = 1.f / fmaxf((float)c, 1.f);
    unsigned int pack = (unsigned int)f2bf(ax * inv)
                      | ((unsigned int)f2bf(ay * inv) << 16);
    ((unsigned int*)tokens)[((size_t)n * 5 + w + 1) * 64 + lane] = pack;
}

// ---------------------------------------------------------------------------
// GEMM1: Z[M,160] = tokens @ [Wd|Wb|Wc] -> delta (softplus), bc.
// N padded to 192; grid (782, 3).
// ---------------------------------------------------------------------------
__global__ __launch_bounds__(256) void mfma_gemm(
    const unsigned short* __restrict__ tokens,
    const unsigned short* __restrict__ Bp,
    const float* __restrict__ b_delta,
    unsigned short* __restrict__ delta,
    unsigned short* __restrict__ bc)
{
    int m0 = blockIdx.x * 64, n0 = blockIdx.y * 64;
    int wv = threadIdx.x >> 6, lane = threadIdx.x & 63;
    int quad = lane >> 4, l16 = lane & 15;

    f32x4 acc[4] = {{0,0,0,0},{0,0,0,0},{0,0,0,0},{0,0,0,0}};
    const unsigned short* arow = tokens + (size_t)(m0 + wv * 16 + l16) * 128 + quad * 8;
    #pragma unroll
    for (int kc = 0; kc < 128; kc += 32) {
        bf16x8 a = *(const bf16x8*)(arow + kc);
        #pragma unroll
        for (int t = 0; t < 4; ++t) {
            bf16x8 b = *(const bf16x8*)(Bp + ((size_t)(kc / 8 + quad) * NPAD + n0 + 16 * t + l16) * 8);
            acc[t] = __builtin_amdgcn_mfma_f32_16x16x32_bf16(a, b, acc[t], 0, 0, 0);
        }
    }

    int rbase = m0 + wv * 16 + quad * 4;
    #pragma unroll
    for (int t = 0; t < 4; ++t) {
        int c = n0 + 16 * t + l16;
        #pragma unroll
        for (int reg = 0; reg < 4; ++reg) {
            int r = rbase + reg;
            if (r >= M_ROWS) continue;
            float v = acc[t][reg];
            if (c < 128) {
                float z = v + b_delta[c];
                float d = (z > 15.f) ? z : log1pf(__expf(z));
                delta[(size_t)r * 128 + c] = f2bf(d);
            } else if (c < 160) {
                bc[(size_t)r * 32 + (c - 128)] = f2bf(v);
            }
        }
    }
}

// ---------------------------------------------------------------------------
// g-GEMM: g[10000,128] = x_bf @ W_g + b_g (x_bf rows == s=0 token rows).
// 157 blocks of 64 rows; pad rows zeroed in prep.
// ---------------------------------------------------------------------------
__global__ __launch_bounds__(256) void g_gemm(
    const unsigned short* __restrict__ x_bf,
    const unsigned short* __restrict__ Wgp,
    const float* __restrict__ b_g,
    unsigned short* __restrict__ g)
{
    int m0 = blockIdx.x * 64;
    int wv = threadIdx.x >> 6, lane = threadIdx.x & 63;
    int quad = lane >> 4, l16 = lane & 15;

    f32x4 acc[8] = {{0,0,0,0},{0,0,0,0},{0,0,0,0},{0,0,0,0},
                    {0,0,0,0},{0,0,0,0},{0,0,0,0},{0,0,0,0}};
    const unsigned short* arow = x_bf + (size_t)(m0 + wv * 16 + l16) * 128 + quad * 8;
    #pragma unroll
    for (int kc = 0; kc < 128; kc += 32) {
        bf16x8 a = *(const bf16x8*)(arow + kc);
        #pragma unroll
        for (int t = 0; t < 8; ++t) {
            bf16x8 b = *(const bf16x8*)(Wgp + ((size_t)(kc / 8 + quad) * 128 + 16 * t + l16) * 8);
            acc[t] = __builtin_amdgcn_mfma_f32_16x16x32_bf16(a, b, acc[t], 0, 0, 0);
        }
    }
    int rbase = m0 + wv * 16 + quad * 4;
    #pragma unroll
    for (int t = 0; t < 8; ++t) {
        int c = 16 * t + l16;
        #pragma unroll
        for (int reg = 0; reg < 4; ++reg) {
            int r = rbase + reg;
            if (r < N_NODES)
                g[(size_t)r * 128 + c] = f2bf(acc[t][reg] + b_g[c]);
        }
    }
}

// ---------------------------------------------------------------------------
// Scan (max width: 10000 blocks x 128 threads, ONE pair per thread).
// Backward scan in forward order via suffix recurrence
// V_{s+1}=A_s*V_s + C_{s+1} (V_0=C_0); y_bwd = sum_s dtv_s*(V_s . B_s).
// ---------------------------------------------------------------------------
__global__ __launch_bounds__(128) void scan_so(
    const unsigned short* __restrict__ tokens,
    const unsigned short* __restrict__ delta,
    const unsigned short* __restrict__ bcbuf,
    const float* __restrict__ log_A,
    unsigned short* __restrict__ so)
{
    const int n = blockIdx.x, t = threadIdx.x;   // t = dim d
    __shared__ __align__(16) float BC[160];      // [s*32 + (B:0-15|C:16-31)]

    for (int idx = t; idx < 160; idx += 128)
        BC[idx] = bf2f(bcbuf[(size_t)n * 160 + idx]);

    float tv[5], dl[5];
    {
        const unsigned short* tb = tokens + (size_t)n * 640 + t;
        const unsigned short* db = delta  + (size_t)n * 640 + t;
        #pragma unroll
        for (int s = 0; s < 5; ++s) {
            tv[s] = bf2f(tb[s * 128]);
            dl[s] = bf2f(db[s * 128]);
        }
    }
    float Ac[16];
    {
        const float4* la = (const float4*)(log_A + t * 16);
        #pragma unroll
        for (int q = 0; q < 4; ++q) {
            float4 lv = la[q];
            Ac[q * 4 + 0] = -__expf(lv.x);
            Ac[q * 4 + 1] = -__expf(lv.y);
            Ac[q * 4 + 2] = -__expf(lv.z);
            Ac[q * 4 + 3] = -__expf(lv.w);
        }
    }
    __syncthreads();

    float st[16], V[16];
    #pragma unroll
    for (int k = 0; k < 16; ++k) { st[k] = 0.f; V[k] = BC[16 + k]; }
    float total = 0.f;
    #pragma unroll
    for (int s = 0; s < 5; ++s) {
        float dtv = dl[s] * tv[s];
        float yf = 0.f, ub = 0.f;
        #pragma unroll
        for (int k = 0; k < 16; ++k) {
            float B = BC[s * 32 + k];
            float C = BC[s * 32 + 16 + k];
            float A = __expf(dl[s] * Ac[k]);
            st[k] = fmaf(A, st[k], dtv * B);
            yf = fmaf(st[k], C, yf);
            ub = fmaf(V[k], B, ub);                  // V_s (pre-update)
            if (s < 4) V[k] = fmaf(A, V[k], BC[(s + 1) * 32 + 16 + k]);
        }
        total += yf + dtv * ub;
    }
    so[(size_t)n * 128 + t] = f2bf(total * 0.2f);
}

// ---------------------------------------------------------------------------
// GEMM2: out = LN(x + silu(g)*(so @ W_out + b_out)). 16-row tiles, 625 blocks.
// ---------------------------------------------------------------------------
__global__ __launch_bounds__(256) void out_gemm(
    const unsigned short* __restrict__ so,
    const unsigned short* __restrict__ Wop,
    const unsigned short* __restrict__ gbuf,
    const float* __restrict__ x,
    const float* __restrict__ b_out,
    const float* __restrict__ ln_g, const float* __restrict__ ln_b,
    float* __restrict__ out)
{
    int m0 = blockIdx.x * 16;
    int tid = threadIdx.x;
    int wv = tid >> 6, lane = tid & 63;
    int quad = lane >> 4, l16 = lane & 15;

    __shared__ float res[16 * 132];
    __shared__ float pmu[16][16];
    __shared__ float pv2[16][16];
    __shared__ float muA[16], rstdA[16];

    f32x4 acc[2] = {{0,0,0,0},{0,0,0,0}};
    const unsigned short* arow = so + (size_t)(m0 + l16) * 128 + quad * 8;
    #pragma unroll
    for (int kc = 0; kc < 128; kc += 32) {
        bf16x8 a = *(const bf16x8*)(arow + kc);
        #pragma unroll
        for (int tt = 0; tt < 2; ++tt) {
            int t = wv * 2 + tt;
            bf16x8 b = *(const bf16x8*)(Wop + ((size_t)(kc / 8 + quad) * 128 + 16 * t + l16) * 8);
            acc[tt] = __builtin_amdgcn_mfma_f32_16x16x32_bf16(a, b, acc[tt], 0, 0, 0);
        }
    }

    #pragma unroll
    for (int tt = 0; tt < 2; ++tt) {
        int c = wv * 32 + tt * 16 + l16;
        #pragma unroll
        for (int reg = 0; reg < 4; ++reg) {
            int lrow = quad * 4 + reg;
            int r = m0 + lrow;
            float o = acc[tt][reg] + b_out[c];
            float gl = bf2f(gbuf[(size_t)r * 128 + c]);
            float gate = gl / (1.f + __expf(-gl));
            res[lrow * 132 + c] = x[(size_t)r * 128 + c] + gate * o;
        }
    }
    __syncthreads();

    {
        int row = tid >> 4, q = tid & 15;
        float s = 0.f, s2 = 0.f;
        #pragma unroll
        for (int i = 0; i < 8; ++i) {
            float v = res[row * 132 + q + 16 * i];
            s += v; s2 += v * v;
        }
        pmu[row][q] = s; pv2[row][q] = s2;
    }
    __syncthreads();
    if (tid < 16) {
        float s = 0.f, s2 = 0.f;
        #pragma unroll
        for (int i = 0; i < 16; ++i) { s += pmu[tid][i]; s2 += pv2[tid][i]; }
        float mu = s * (1.f / 128.f);
        float var = s2 * (1.f / 128.f) - mu * mu;
        muA[tid] = mu;
        rstdA[tid] = rsqrtf(var + LN_EPS);
    }
    __syncthreads();
    #pragma unroll
    for (int i = 0; i < 8; ++i) {
        int idx = i * 256 + tid;
        int row = idx >> 7, c = idx & 127;
        out[(size_t)(m0 + row) * 128 + c] =
            (res[row * 132 + c] - muA[row]) * rstdA[row] * ln_g[c] + ln_b[c];
    }
}

// ---------------------------------------------------------------------------
extern "C" void kernel_launch(void* const* d_in, const int* in_sizes, int n_in,
                              void* d_out, int out_size, void* d_ws, size_t ws_size,
                              hipStream_t stream) {
    const float* x          = (const float*)d_in[0];
    const int*   edge_index = (const int*)  d_in[1];
    const int*   edge_type  = (const int*)  d_in[2];
    const int*   perms      = (const int*)  d_in[3];
    const float* rel_table  = (const float*)d_in[4];
    const float* log_A      = (const float*)d_in[5];
    const float* W_B        = (const float*)d_in[6];
    const float* W_C        = (const float*)d_in[7];
    const float* W_delta    = (const float*)d_in[8];
    const float* b_delta    = (const float*)d_in[9];
    const float* W_g        = (const float*)d_in[10];
    const float* b_g        = (const float*)d_in[11];
    const float* W_out      = (const float*)d_in[12];
    const float* b_out      = (const float*)d_in[13];
    const float* ln_g       = (const float*)d_in[14];
    const float* ln_b       = (const float*)d_in[15];

    char* ws = (char*)d_ws;
    int*            cnt    = (int*)           (ws + 0);          //   163840
    unsigned short* Bp     = (unsigned short*)(ws + 163840);     //    49152
    unsigned short* Wgp    = (unsigned short*)(ws + 212992);     //    32768
    unsigned short* Wop    = (unsigned short*)(ws + 245760);     //    32768
    unsigned short* x_bf   = (unsigned short*)(ws + 278528);     //  2572288 (10048 rows)
    unsigned short* rel_bf = (unsigned short*)(ws + 2850816);    //    51200
    int4*           ed4    = (int4*)          (ws + 2902016);    //  5120000
    unsigned short* tokens = (unsigned short*)(ws + 8022016);    // 12800000
    unsigned short* g      = (unsigned short*)(ws + 20822016);   //  2560000
    unsigned short* bc     = (unsigned short*)(ws + 23382016);   //  3200000
    // union: slots (consumed by gather) aliased with delta (written by gemm1)
    int2*           slots  = (int2*)          (ws + 26582016);   // 10485760
    unsigned short* delta  = (unsigned short*)(ws + 26582016);   // 12800000
    unsigned short* so     = (unsigned short*)(ws + 39394304);   //  2560000

    prep_all<<<(1730048 + 255) / 256, 256, 0, stream>>>(
        W_delta, W_B, W_C, W_g, W_out, x, rel_table, edge_index, edge_type,
        Bp, Wgp, Wop, x_bf, rel_bf, cnt, ed4, tokens);

    csr_build<<<(4 * P_EDGES + 255) / 256, 256, 0, stream>>>(
        ed4, perms, cnt, slots);

    gather_tokens<<<N_NODES, 256, 0, stream>>>(
        x_bf, cnt, slots, rel_bf, tokens);

    mfma_gemm<<<dim3(M_PAD / 64, 3), 256, 0, stream>>>(
        tokens, Bp, b_delta, delta, bc);

    g_gemm<<<157, 256, 0, stream>>>(x_bf, Wgp, b_g, g);

    scan_so<<<N_NODES, 128, 0, stream>>>(
        tokens, delta, bc, log_A, so);

    out_gemm<<<N_NODES / 16, 256, 0, stream>>>(
        so, Wop, g, x, b_out, ln_g, ln_b, (float*)d_out);
}

// Round 13
// 198.852 us; speedup vs baseline: 1.0224x; 1.0224x over previous
//
#include <hip/hip_runtime.h>
#include <hip/hip_bf16.h>
#include <math.h>

#define N_NODES 10000
#define D_MODEL 128
#define E_EDGES 320000
#define P_EDGES 80000
#define LN_EPS 1e-5f
#define NBUCK 40960        // 4*N padded
#define CAP 32             // slots per bucket (Poisson(8): P(>32) ~ 1e-11)
#define M_ROWS 50000
#define M_PAD  50048       // 782*64
#define NPAD   320         // 288 cols padded

typedef __attribute__((ext_vector_type(8))) short bf16x8;
typedef __attribute__((ext_vector_type(4))) float f32x4;

__device__ __forceinline__ unsigned short f2bf(float f) {
    __hip_bfloat16 h = __float2bfloat16(f);
    return *reinterpret_cast<unsigned short*>(&h);
}
__device__ __forceinline__ float bf2f(unsigned int u) {
    return __uint_as_float(u << 16);
}

// ---------------------------------------------------------------------------
// prep_all: pack Wcat + W_out (B-frag layout), x/rel -> bf16 (x also straight
// into the s=0 token rows), zero counters, pack edge triples into ed4.
// ---------------------------------------------------------------------------
__global__ __launch_bounds__(256) void prep_all(
    const float* __restrict__ Wd, const float* __restrict__ Wb,
    const float* __restrict__ Wc, const float* __restrict__ Wg,
    const float* __restrict__ W_out,
    const float* __restrict__ x, const float* __restrict__ rel,
    const int* __restrict__ edge_index, const int* __restrict__ edge_type,
    unsigned short* __restrict__ Bp, unsigned short* __restrict__ Wop,
    unsigned short* __restrict__ x_bf, unsigned short* __restrict__ rel_bf,
    int* __restrict__ cnt, int4* __restrict__ ed4,
    unsigned short* __restrict__ tokens)
{
    int gid = blockIdx.x * 256 + threadIdx.x;
    if (gid < 40960) {
        int k = gid / NPAD, n = gid - (gid / NPAD) * NPAD;
        float v = 0.f;
        if (n < 128)      v = Wd[k * 128 + n];
        else if (n < 144) v = Wb[k * 16 + (n - 128)];
        else if (n < 160) v = Wc[k * 16 + (n - 144)];
        else if (n < 288) v = Wg[k * 128 + (n - 160)];
        Bp[((size_t)(k >> 3) * NPAD + n) * 8 + (k & 7)] = f2bf(v);
    } else if (gid < 57344) {
        int i = gid - 40960;
        int k = i >> 7, n = i & 127;
        Wop[((size_t)(k >> 3) * 128 + n) * 8 + (k & 7)] = f2bf(W_out[k * 128 + n]);
    } else if (gid < 98304) {
        cnt[gid - 57344] = 0;
    } else if (gid < 123904) {
        int i = gid - 98304;
        rel_bf[i] = f2bf(rel[i]);
    } else if (gid < 1403904) {
        int i = gid - 123904;
        unsigned short v = f2bf(x[i]);
        x_bf[i] = v;
        tokens[(size_t)(i >> 7) * 640 + (i & 127)] = v;   // s=0 token row
    } else if (gid < 1723904) {
        int e = gid - 1403904;
        ed4[e] = make_int4(edge_index[e], edge_index[E_EDGES + e], edge_type[e], 0);
    }
}

// ---------------------------------------------------------------------------
// One-pass CSR into fixed-capacity bucket slots (1 random 16B load per edge).
// ---------------------------------------------------------------------------
__global__ __launch_bounds__(256) void csr_build(
    const int4* __restrict__ ed4, const int* __restrict__ perms,
    int* __restrict__ cnt, int2* __restrict__ slots)
{
    int gid = blockIdx.x * blockDim.x + threadIdx.x;
    if (gid >= 4 * P_EDGES) return;
    int s = gid / P_EDGES;
    int e = perms[gid];
    int4 ed = ed4[e];
    int b = ed.y * 4 + s;
    int pos = atomicAdd(&cnt[b], 1);
    if (pos < CAP) slots[(size_t)b * CAP + pos] = make_int2(ed.x, ed.z);
}

// ---------------------------------------------------------------------------
// Gather (wide: 10000 blocks): one wave per bucket; lane = 2 dims;
// 4 edges in flight.
// ---------------------------------------------------------------------------
__global__ __launch_bounds__(256) void gather_tokens(
    const unsigned short* __restrict__ x_bf,
    const int* __restrict__ cnt, const int2* __restrict__ slots,
    const unsigned short* __restrict__ rel_bf,
    unsigned short* __restrict__ tokens)
{
    int n = blockIdx.x;
    int w = threadIdx.x >> 6, lane = threadIdx.x & 63;
    int b = n * 4 + w;
    int c = cnt[b];
    int cc = c < CAP ? c : CAP;
    const int2* sl = slots + (size_t)b * CAP;
    const unsigned int* xu = (const unsigned int*)x_bf;
    const unsigned int* ru = (const unsigned int*)rel_bf;
    float ax = 0.f, ay = 0.f;
    int j = 0;
    for (; j + 4 <= cc; j += 4) {
        int4 e01 = *(const int4*)(sl + j);
        int4 e23 = *(const int4*)(sl + j + 2);
        unsigned int x0 = xu[(size_t)e01.x * 64 + lane];
        unsigned int r0 = ru[(size_t)e01.y * 64 + lane];
        unsigned int x1 = xu[(size_t)e01.z * 64 + lane];
        unsigned int r1 = ru[(size_t)e01.w * 64 + lane];
        unsigned int x2 = xu[(size_t)e23.x * 64 + lane];
        unsigned int r2 = ru[(size_t)e23.y * 64 + lane];
        unsigned int x3 = xu[(size_t)e23.z * 64 + lane];
        unsigned int r3 = ru[(size_t)e23.w * 64 + lane];
        ax += (bf2f(x0 & 0xffffu) + bf2f(r0 & 0xffffu))
            + (bf2f(x1 & 0xffffu) + bf2f(r1 & 0xffffu))
            + (bf2f(x2 & 0xffffu) + bf2f(r2 & 0xffffu))
            + (bf2f(x3 & 0xffffu) + bf2f(r3 & 0xffffu));
        ay += (bf2f(x0 >> 16) + bf2f(r0 >> 16))
            + (bf2f(x1 >> 16) + bf2f(r1 >> 16))
            + (bf2f(x2 >> 16) + bf2f(r2 >> 16))
            + (bf2f(x3 >> 16) + bf2f(r3 >> 16));
    }
    if (j + 2 <= cc) {
        int4 e01 = *(const int4*)(sl + j);
        unsigned int x0 = xu[(size_t)e01.x * 64 + lane];
        unsigned int r0 = ru[(size_t)e01.y * 64 + lane];
        unsigned int x1 = xu[(size_t)e01.z * 64 + lane];
        unsigned int r1 = ru[(size_t)e01.w * 64 + lane];
        ax += (bf2f(x0 & 0xffffu) + bf2f(r0 & 0xffffu))
            + (bf2f(x1 & 0xffffu) + bf2f(r1 & 0xffffu));
        ay += (bf2f(x0 >> 16) + bf2f(r0 >> 16))
            + (bf2f(x1 >> 16) + bf2f(r1 >> 16));
        j += 2;
    }
    if (j < cc) {
        int2 se = sl[j];
        unsigned int xa = xu[(size_t)se.x * 64 + lane];
        unsigned int ra = ru[(size_t)se.y * 64 + lane];
        ax += bf2f(xa & 0xffffu) + bf2f(ra & 0xffffu);
        ay += bf2f(xa >> 16) + bf2f(ra >> 16);
    }
    float inv = 1.f / fmaxf((float)c, 1.f);
    unsigned int pack = (unsigned int)f2bf(ax * inv)
                      | ((unsigned int)f2bf(ay * inv) << 16);
    ((unsigned int*)tokens)[((size_t)n * 5 + w + 1) * 64 + lane] = pack;
}

// ---------------------------------------------------------------------------
// GEMM1: Z[M,288] = tokens @ Wcat -> delta (softplus), bc, g. 3910 blocks.
// ---------------------------------------------------------------------------
__global__ __launch_bounds__(256) void mfma_gemm(
    const unsigned short* __restrict__ tokens,
    const unsigned short* __restrict__ Bp,
    const float* __restrict__ b_delta, const float* __restrict__ b_g,
    unsigned short* __restrict__ delta,
    unsigned short* __restrict__ bc,
    unsigned short* __restrict__ g)
{
    int m0 = blockIdx.x * 64, n0 = blockIdx.y * 64;
    int wv = threadIdx.x >> 6, lane = threadIdx.x & 63;
    int quad = lane >> 4, l16 = lane & 15;

    f32x4 acc[4] = {{0,0,0,0},{0,0,0,0},{0,0,0,0},{0,0,0,0}};
    const unsigned short* arow = tokens + (size_t)(m0 + wv * 16 + l16) * 128 + quad * 8;
    #pragma unroll
    for (int kc = 0; kc < 128; kc += 32) {
        bf16x8 a = *(const bf16x8*)(arow + kc);
        #pragma unroll
        for (int t = 0; t < 4; ++t) {
            bf16x8 b = *(const bf16x8*)(Bp + ((size_t)(kc / 8 + quad) * NPAD + n0 + 16 * t + l16) * 8);
            acc[t] = __builtin_amdgcn_mfma_f32_16x16x32_bf16(a, b, acc[t], 0, 0, 0);
        }
    }

    int rbase = m0 + wv * 16 + quad * 4;
    #pragma unroll
    for (int t = 0; t < 4; ++t) {
        int c = n0 + 16 * t + l16;
        #pragma unroll
        for (int reg = 0; reg < 4; ++reg) {
            int r = rbase + reg;
            if (r >= M_ROWS) continue;
            float v = acc[t][reg];
            if (c < 128) {
                float z = v + b_delta[c];
                float d = (z > 15.f) ? z : log1pf(__expf(z));
                delta[(size_t)r * 128 + c] = f2bf(d);
            } else if (c < 160) {
                bc[(size_t)r * 32 + (c - 128)] = f2bf(v);
            } else if (c < 288) {
                int rq = r / 5;
                if (r - rq * 5 == 0)
                    g[(size_t)rq * 128 + (c - 160)] = f2bf(v + b_g[c - 160]);
            }
        }
    }
}

// ---------------------------------------------------------------------------
// Scan (max width: 10000 blocks x 128 threads, ONE pair per thread).
// Backward scan in forward order via suffix recurrence
// V_{s+1}=A_s*V_s + C_{s+1} (V_0=C_0); y_bwd = sum_s dtv_s*(V_s . B_s).
// No Af stash -> low VGPR -> high occupancy; 20000 waves hide all latency.
// ---------------------------------------------------------------------------
__global__ __launch_bounds__(128) void scan_so(
    const unsigned short* __restrict__ tokens,
    const unsigned short* __restrict__ delta,
    const unsigned short* __restrict__ bcbuf,
    const float* __restrict__ log_A,
    unsigned short* __restrict__ so)
{
    const int n = blockIdx.x, t = threadIdx.x;   // t = dim d
    __shared__ __align__(16) float BC[160];      // [s*32 + (B:0-15|C:16-31)]

    for (int idx = t; idx < 160; idx += 128)
        BC[idx] = bf2f(bcbuf[(size_t)n * 160 + idx]);

    float tv[5], dl[5];
    {
        const unsigned short* tb = tokens + (size_t)n * 640 + t;
        const unsigned short* db = delta  + (size_t)n * 640 + t;
        #pragma unroll
        for (int s = 0; s < 5; ++s) {
            tv[s] = bf2f(tb[s * 128]);
            dl[s] = bf2f(db[s * 128]);
        }
    }
    float Ac[16];
    {
        const float4* la = (const float4*)(log_A + t * 16);
        #pragma unroll
        for (int q = 0; q < 4; ++q) {
            float4 lv = la[q];
            Ac[q * 4 + 0] = -__expf(lv.x);
            Ac[q * 4 + 1] = -__expf(lv.y);
            Ac[q * 4 + 2] = -__expf(lv.z);
            Ac[q * 4 + 3] = -__expf(lv.w);
        }
    }
    __syncthreads();

    float st[16], V[16];
    #pragma unroll
    for (int k = 0; k < 16; ++k) { st[k] = 0.f; V[k] = BC[16 + k]; }
    float total = 0.f;
    #pragma unroll
    for (int s = 0; s < 5; ++s) {
        float dtv = dl[s] * tv[s];
        float yf = 0.f, ub = 0.f;
        #pragma unroll
        for (int k = 0; k < 16; ++k) {
            float B = BC[s * 32 + k];
            float C = BC[s * 32 + 16 + k];
            float A = __expf(dl[s] * Ac[k]);
            st[k] = fmaf(A, st[k], dtv * B);
            yf = fmaf(st[k], C, yf);
            ub = fmaf(V[k], B, ub);                  // V_s (pre-update)
            if (s < 4) V[k] = fmaf(A, V[k], BC[(s + 1) * 32 + 16 + k]);
        }
        total += yf + dtv * ub;
    }
    so[(size_t)n * 128 + t] = f2bf(total * 0.2f);
}

// ---------------------------------------------------------------------------
// GEMM2: out = LN(x + silu(g)*(so @ W_out + b_out)). 16-row tiles, 625 blocks.
// ---------------------------------------------------------------------------
__global__ __launch_bounds__(256) void out_gemm(
    const unsigned short* __restrict__ so,
    const unsigned short* __restrict__ Wop,
    const unsigned short* __restrict__ gbuf,
    const float* __restrict__ x,
    const float* __restrict__ b_out,
    const float* __restrict__ ln_g, const float* __restrict__ ln_b,
    float* __restrict__ out)
{
    int m0 = blockIdx.x * 16;
    int tid = threadIdx.x;
    int wv = tid >> 6, lane = tid & 63;
    int quad = lane >> 4, l16 = lane & 15;

    __shared__ float res[16 * 132];
    __shared__ float pmu[16][16];
    __shared__ float pv2[16][16];
    __shared__ float muA[16], rstdA[16];

    f32x4 acc[2] = {{0,0,0,0},{0,0,0,0}};
    const unsigned short* arow = so + (size_t)(m0 + l16) * 128 + quad * 8;
    #pragma unroll
    for (int kc = 0; kc < 128; kc += 32) {
        bf16x8 a = *(const bf16x8*)(arow + kc);
        #pragma unroll
        for (int tt = 0; tt < 2; ++tt) {
            int t = wv * 2 + tt;
            bf16x8 b = *(const bf16x8*)(Wop + ((size_t)(kc / 8 + quad) * 128 + 16 * t + l16) * 8);
            acc[tt] = __builtin_amdgcn_mfma_f32_16x16x32_bf16(a, b, acc[tt], 0, 0, 0);
        }
    }

    #pragma unroll
    for (int tt = 0; tt < 2; ++tt) {
        int c = wv * 32 + tt * 16 + l16;
        #pragma unroll
        for (int reg = 0; reg < 4; ++reg) {
            int lrow = quad * 4 + reg;
            int r = m0 + lrow;
            float o = acc[tt][reg] + b_out[c];
            float gl = bf2f(gbuf[(size_t)r * 128 + c]);
            float gate = gl / (1.f + __expf(-gl));
            res[lrow * 132 + c] = x[(size_t)r * 128 + c] + gate * o;
        }
    }
    __syncthreads();

    {
        int row = tid >> 4, q = tid & 15;
        float s = 0.f, s2 = 0.f;
        #pragma unroll
        for (int i = 0; i < 8; ++i) {
            float v = res[row * 132 + q + 16 * i];
            s += v; s2 += v * v;
        }
        pmu[row][q] = s; pv2[row][q] = s2;
    }
    __syncthreads();
    if (tid < 16) {
        float s = 0.f, s2 = 0.f;
        #pragma unroll
        for (int i = 0; i < 16; ++i) { s += pmu[tid][i]; s2 += pv2[tid][i]; }
        float mu = s * (1.f / 128.f);
        float var = s2 * (1.f / 128.f) - mu * mu;
        muA[tid] = mu;
        rstdA[tid] = rsqrtf(var + LN_EPS);
    }
    __syncthreads();
    #pragma unroll
    for (int i = 0; i < 8; ++i) {
        int idx = i * 256 + tid;
        int row = idx >> 7, c = idx & 127;
        out[(size_t)(m0 + row) * 128 + c] =
            (res[row * 132 + c] - muA[row]) * rstdA[row] * ln_g[c] + ln_b[c];
    }
}

// ---------------------------------------------------------------------------
extern "C" void kernel_launch(void* const* d_in, const int* in_sizes, int n_in,
                              void* d_out, int out_size, void* d_ws, size_t ws_size,
                              hipStream_t stream) {
    const float* x          = (const float*)d_in[0];
    const int*   edge_index = (const int*)  d_in[1];
    const int*   edge_type  = (const int*)  d_in[2];
    const int*   perms      = (const int*)  d_in[3];
    const float* rel_table  = (const float*)d_in[4];
    const float* log_A      = (const float*)d_in[5];
    const float* W_B        = (const float*)d_in[6];
    const float* W_C        = (const float*)d_in[7];
    const float* W_delta    = (const float*)d_in[8];
    const float* b_delta    = (const float*)d_in[9];
    const float* W_g        = (const float*)d_in[10];
    const float* b_g        = (const float*)d_in[11];
    const float* W_out      = (const float*)d_in[12];
    const float* b_out      = (const float*)d_in[13];
    const float* ln_g       = (const float*)d_in[14];
    const float* ln_b       = (const float*)d_in[15];

    char* ws = (char*)d_ws;
    int*            cnt    = (int*)           (ws + 0);          //   163840
    unsigned short* Bp     = (unsigned short*)(ws + 163840);     //    81920
    unsigned short* Wop    = (unsigned short*)(ws + 245760);     //    32768
    unsigned short* x_bf   = (unsigned short*)(ws + 278528);     //  2560000
    unsigned short* rel_bf = (unsigned short*)(ws + 2838528);    //    51200
    int4*           ed4    = (int4*)          (ws + 2889728);    //  5120000
    unsigned short* tokens = (unsigned short*)(ws + 8009728);    // 12812288
    unsigned short* g      = (unsigned short*)(ws + 20822016);   //  2560000
    unsigned short* bc     = (unsigned short*)(ws + 23382016);   //  3200000
    // union: slots (consumed by gather) aliased with delta (written by gemm1)
    int2*           slots  = (int2*)          (ws + 26582016);   // 10485760
    unsigned short* delta  = (unsigned short*)(ws + 26582016);   // 12812288
    unsigned short* so     = (unsigned short*)(ws + 39394304);   //  2560000

    prep_all<<<(1723904 + 255) / 256, 256, 0, stream>>>(
        W_delta, W_B, W_C, W_g, W_out, x, rel_table, edge_index, edge_type,
        Bp, Wop, x_bf, rel_bf, cnt, ed4, tokens);

    csr_build<<<(4 * P_EDGES + 255) / 256, 256, 0, stream>>>(
        ed4, perms, cnt, slots);

    gather_tokens<<<N_NODES, 256, 0, stream>>>(
        x_bf, cnt, slots, rel_bf, tokens);

    mfma_gemm<<<dim3(M_PAD / 64, NPAD / 64), 256, 0, stream>>>(
        tokens, Bp, b_delta, b_g, delta, bc, g);

    scan_so<<<N_NODES, 128, 0, stream>>>(
        tokens, delta, bc, log_A, so);

    out_gemm<<<N_NODES / 16, 256, 0, stream>>>(
        so, Wop, g, x, b_out, ln_g, ln_b, (float*)d_out);
}